// Round 17
// baseline (252.693 us; speedup 1.0000x reference)
//
#include <hip/hip_runtime.h>

// adder2d: out[b,f,l] = -sum_k |W[f,k] - P[b,k,l]|, P = 3x3/s1/p1 im2col of x.
// Round-17: r16 main (4-wave blocks, 64m x 128f, shared staging, v_sad_u16
// u16-quant BC=8, single-buffer LDS, two raw barriers/chunk, K-split x4 over
// blockIdx.z) with the slab+combine replaced by FIRE-AND-FORGET atomics:
// each split-block atomicAdd's -(acc/QS) into out (fp32-exact: all values
// are multiples of 2^-12 with |out|*4096 < 2^24, so order is irrelevant and
// the result is bit-deterministic). No fences (r15's failure), no slabs,
// no combine kernel. out pre-zeroed by hipMemsetAsync (graph-legal).

#define B_    16
#define C_    128
#define HH    28
#define WW    28
#define F_    128
#define L_    (HH * WW)          // 784
#define K_    (C_ * 9)           // 1152
#define M_    (B_ * L_)          // 12544 = 196 * 64 exactly
#define TM    64
#define BC    8                  // channels per chunk
#define KC    (BC * 9)           // 72 k per chunk
#define KP    (KC / 2)           // 36 packed pairs per chunk
#define NMT   (M_ / TM)          // 196 m-tiles
#define NSP   4                  // K-split factor (blocks over blockIdx.z)
#define NCH   ((C_ / BC) / NSP)  // 4 chunks per block
#define QS    4096.0f            // u16 quantization scale (range +-8)
#define QB    32768.5f           // bias + 0.5 (round-half-up via cvt floor)

__device__ __forceinline__ unsigned sad16(unsigned a, unsigned b, unsigned c) {
    // D = |a.lo16 - b.lo16| + |a.hi16 - b.hi16| + c   (2 elems / inst)
    asm("v_sad_u16 %0, %1, %2, %0" : "+v"(c) : "v"(a), "v"(b));
    return c;
}

__global__ __launch_bounds__(256, 4)
void adder2d_main(const float* __restrict__ x, const float* __restrict__ Wg,
                  float* __restrict__ out) {
    __shared__ __align__(16) unsigned Plq[KP][TM];   //  9,216 B
    __shared__ __align__(16) unsigned Wlq[KP][F_];   // 18,432 B

    const int t    = threadIdx.x;       // 0..255
    const int lane = t & 63;
    const int w    = t >> 6;            // wave 0..3
    const int tx   = lane & 7;          // m-group: 8 m each
    const int ty   = lane >> 3;         // f-group: 4 f each
    const int fw   = 32 * w;            // wave's f slice base
    const int mt   = blockIdx.x, sp = blockIdx.z;
    const int c0   = sp * NCH * BC;

    // ---- P identity: lane owns m = mt*64 + lane (same set in every wave) ----
    const int m  = mt * TM + lane;
    const int b  = m / L_;
    const int l  = m - b * L_;
    const int ho = l / WW, wo = l - ho * WW;
    int   toff[9];
    float sc[9];
    #pragma unroll
    for (int r = 0; r < 9; ++r) {
        const int dy = r / 3 - 1;
        const int dx = r - (r / 3) * 3 - 1;
        const bool ok = ((unsigned)(ho + dy) < (unsigned)HH) &&
                        ((unsigned)(wo + dx) < (unsigned)WW);
        toff[r] = ok ? (dy * WW + dx) : 0;   // safe addr; zeroed by sc
        sc[r]   = ok ? QS : 0.0f;            // masked -> quantize(0) = bias
    }
    const float* xb = x + (size_t)b * (C_ * L_) + l;

    // ---- staging roles (wave-uniform) ----
    // P: wave w stages pair rows [w*9, w*9+9): channels (c8+pb, c8+pb+2),
    //    pb = (w&1) + 4*(w>>1)  -> pairs (0,2)(1,3)(4,6)(5,7). Taps 0..8.
    const int pb = (w & 1) + 4 * (w >> 1);
    // W: thread owns row fW = t>>1, half pW = t&1 -> row-groups g = pW + 2s.
    const int fW = t >> 1;
    const int pW = t & 1;
    const float* wbase = Wg + (size_t)fW * K_;

    unsigned acc[8][4];
    #pragma unroll
    for (int i = 0; i < 8; ++i)
        #pragma unroll
        for (int j = 0; j < 4; ++j) acc[i][j] = 0u;

    float ppre[18];     // P: 9 taps x 2 channels
    auto loadP = [&](int c8) {
        const float* x1 = xb + (size_t)(c8 + pb) * L_;
        const float* x2 = x1 + 2 * L_;
        #pragma unroll
        for (int r = 0; r < 9; ++r) {
            ppre[r]     = x1[toff[r]];
            ppre[9 + r] = x2[toff[r]];
        }
    };

    loadP(c0);

    #pragma unroll 1
    for (int ch = 0; ch < NCH; ++ch) {
        const int c8 = c0 + ch * BC;
        // ---- P: write staged regs -> LDS (quantize + pack inline) ----
        #pragma unroll
        for (int r = 0; r < 9; ++r) {
            const unsigned qlo = (unsigned)__builtin_fmaf(ppre[r],     sc[r], QB);
            const unsigned qhi = (unsigned)__builtin_fmaf(ppre[9 + r], sc[r], QB);
            Plq[w * 9 + r][lane] = (qlo & 0xffffu) | (qhi << 16);
        }
        // ---- W: direct from L2, quantize + pack ----
        #pragma unroll
        for (int s = 0; s < 2; ++s) {
            const float* w1 = wbase + (size_t)(c8 + pW + 4 * s) * 9;
            #pragma unroll
            for (int i = 0; i < 9; ++i) {
                const unsigned qlo = (unsigned)__builtin_fmaf(w1[i],      QS, QB);
                const unsigned qhi = (unsigned)__builtin_fmaf(w1[i + 18], QS, QB);
                Wlq[(pW + 2 * s) * 9 + i][fW] = (qlo & 0xffffu) | (qhi << 16);
            }
        }
        // ---- prefetch next chunk P (stays in flight across the barrier) ----
        if (ch + 1 < NCH) loadP(c8 + BC);
        // ---- barrier A: LDS writes drained, P-prefetch vmcnt NOT drained ----
        asm volatile("s_waitcnt lgkmcnt(0)" ::: "memory");
        __builtin_amdgcn_s_barrier();
        asm volatile("" ::: "memory");
        __builtin_amdgcn_sched_barrier(0);
        // ---- compute: 36 kp x (3 ds_read_b128 + 32 v_sad_u16) ----
        #pragma unroll 6
        for (int kp = 0; kp < KP; ++kp) {
            const uint4 pA = *(const uint4*)&Plq[kp][tx * 8];
            const uint4 pB = *(const uint4*)&Plq[kp][tx * 8 + 4];
            const uint4 wA = *(const uint4*)&Wlq[kp][fw + ty * 4];
            const unsigned pm[8] = {pA.x, pA.y, pA.z, pA.w,
                                    pB.x, pB.y, pB.z, pB.w};
            const unsigned wn[4] = {wA.x, wA.y, wA.z, wA.w};
            #pragma unroll
            for (int i = 0; i < 8; ++i)
                #pragma unroll
                for (int j = 0; j < 4; ++j)
                    acc[i][j] = sad16(pm[i], wn[j], acc[i][j]);
        }
        // ---- barrier B: reads of this buffer consumed before next writes ----
        if (ch + 1 < NCH) {
            asm volatile("" ::: "memory");
            __builtin_amdgcn_sched_barrier(0);
            __builtin_amdgcn_s_barrier();
            asm volatile("" ::: "memory");
        }
    }

    // ---- epilogue: fire-and-forget atomic accumulation into out ----
    // thread covers m = mt*64 + tx*8 .. +8 (8 | 784: no image straddle)
    const int mb = mt * TM + tx * 8;
    const int bI = mb / L_;
    const int lb = mb - bI * L_;
    const float qs = -1.0f / QS;            // dequant + sign fold
    #pragma unroll
    for (int j = 0; j < 4; ++j) {
        const int f = fw + ty * 4 + j;
        float* o = &out[(size_t)(bI * F_ + f) * L_ + lb];
        #pragma unroll
        for (int i = 0; i < 8; ++i)
            atomicAdd(o + i, qs * (float)acc[i][j]);
    }
}

extern "C" void kernel_launch(void* const* d_in, const int* in_sizes, int n_in,
                              void* d_out, int out_size, void* d_ws, size_t ws_size,
                              hipStream_t stream) {
    const float* x = (const float*)d_in[0];   // [16,128,28,28]
    const float* W = (const float*)d_in[1];   // [128,128,3,3]
    float* out = (float*)d_out;               // [16,128,28,28]
    (void)d_ws; (void)ws_size;

    hipMemsetAsync(out, 0, (size_t)B_ * F_ * L_ * sizeof(float), stream);
    dim3 grid(NMT, 1, NSP);                   // (196,1,4) = 784 4-wave blocks
    adder2d_main<<<grid, 256, 0, stream>>>(x, W, out);
}

// Round 18
// 120.582 us; speedup vs baseline: 2.0956x; 2.0956x over previous
//
#include <hip/hip_runtime.h>

// adder2d: out[b,f,l] = -sum_k |W[f,k] - P[b,k,l]|, P = 3x3/s1/p1 im2col of x.
// Round-18: two-kernel slab structure (proven r14/r16; fusion refuted r15/r17)
// with the block tile grown to 128m x 128f (4 waves, per-thread 8m x 8f):
// per kp = 4 ds_read_b128 for 64 v_sad_u16 (16 sads/read, was 10.7) ->
// LDS-read stream 26.6 -> 17.7us < VALU 23.6us: VALU becomes the binder.
// Wave w: m-half = w>>1, f-half = w&1. P and W staged direct from L2
// (no reg-prefetch -> ~110 VGPR, launch_bounds(256,2), no spill).
// Single-buffer LDS 36.9KB, two raw barriers/chunk, BC=8, nsp=8, NCH=2.

#define B_    16
#define C_    128
#define HH    28
#define WW    28
#define F_    128
#define L_    (HH * WW)          // 784
#define K_    (C_ * 9)           // 1152
#define M_    (B_ * L_)          // 12544 = 98 * 128 exactly
#define TM    128
#define BC    8                  // channels per chunk
#define KC    (BC * 9)           // 72 k per chunk
#define KP    (KC / 2)           // 36 packed pairs per chunk
#define NMT   (M_ / TM)          // 98 m-tiles
#define NSP   8                  // K-split factor
#define NCH   ((C_ / BC) / NSP)  // 2 chunks per block
#define SLAB  (B_ * F_ * L_)     // 1,605,632 floats per partial slab
#define QS    4096.0f            // u16 quantization scale (range +-8)
#define QB    32768.5f           // bias + 0.5 (round-half-up via cvt floor)

__device__ __forceinline__ unsigned sad16(unsigned a, unsigned b, unsigned c) {
    // D = |a.lo16 - b.lo16| + |a.hi16 - b.hi16| + c   (2 elems / inst)
    asm("v_sad_u16 %0, %1, %2, %0" : "+v"(c) : "v"(a), "v"(b));
    return c;
}

__global__ __launch_bounds__(256, 2)
void adder2d_main(const float* __restrict__ x, const float* __restrict__ Wg,
                  float* __restrict__ dst, int nch, int direct) {
    __shared__ __align__(16) unsigned Plq[KP][TM];   // 18,432 B
    __shared__ __align__(16) unsigned Wlq[KP][F_];   // 18,432 B

    const int t    = threadIdx.x;       // 0..255
    const int lane = t & 63;
    const int w    = t >> 6;            // wave 0..3
    const int tx   = lane & 7;          // m-group: 8 m each
    const int ty   = lane >> 3;         // f-group: 8 f each
    const int mh   = w >> 1;            // wave's m-half (0/1)
    const int fh   = w & 1;             // wave's f-half (0/1)
    const int mt   = blockIdx.x, sp = blockIdx.z;
    const int c0   = sp * NCH * BC;

    // ---- staging identity: thread owns P column mcs = t&127, group g = t>>7
    const int mcs = t & 127;
    const int g   = t >> 7;
    const int ms  = mt * TM + mcs;
    const int bs  = ms / L_;
    const int ls  = ms - bs * L_;
    const int hos = ls / WW, wos = ls - (ls / WW) * WW;
    int   toff[9];
    float sc[9];
    #pragma unroll
    for (int r = 0; r < 9; ++r) {
        const int dy = r / 3 - 1;
        const int dx = r - (r / 3) * 3 - 1;
        const bool ok = ((unsigned)(hos + dy) < (unsigned)HH) &&
                        ((unsigned)(wos + dx) < (unsigned)WW);
        toff[r] = ok ? (dy * WW + dx) : 0;   // safe addr; zeroed by sc
        sc[r]   = ok ? QS : 0.0f;            // masked -> quantize(0) = bias
    }
    const float* xbs = x + (size_t)bs * (C_ * L_) + ls;
    // W staging: thread owns row fWs = t&127, group g (same split).
    const float* wrow = Wg + (size_t)mcs * K_;   // fWs == mcs numerically

    unsigned acc[8][8];
    #pragma unroll
    for (int i = 0; i < 8; ++i)
        #pragma unroll
        for (int j = 0; j < 8; ++j) acc[i][j] = 0u;

    #pragma unroll 1
    for (int ch = 0; ch < nch; ++ch) {
        const int c8 = c0 + ch * BC;
        // ---- stage P: 2 pair-rows (g-split), 36 gathers, quantize+pack ----
        #pragma unroll
        for (int pp = 0; pp < 2; ++pp) {
            const int pr = 2 * g + pp;                    // pair row 0..3
            const int lo = (pr & 1) + 4 * (pr >> 1);      // (0,2)(1,3)(4,6)(5,7)
            const float* x1 = xbs + (size_t)(c8 + lo) * L_;
            const float* x2 = x1 + 2 * L_;
            #pragma unroll
            for (int r = 0; r < 9; ++r) {
                const unsigned qlo = (unsigned)__builtin_fmaf(x1[toff[r]], sc[r], QB);
                const unsigned qhi = (unsigned)__builtin_fmaf(x2[toff[r]], sc[r], QB);
                Plq[pr * 9 + r][mcs] = (qlo & 0xffffu) | (qhi << 16);
            }
        }
        // ---- stage W: 2 pair-rows, 9+9 consecutive loads each ----
        #pragma unroll
        for (int pp = 0; pp < 2; ++pp) {
            const int pr = 2 * g + pp;
            const int lo = (pr & 1) + 4 * (pr >> 1);
            const float* w1 = wrow + (size_t)(c8 + lo) * 9;
            #pragma unroll
            for (int r = 0; r < 9; ++r) {
                const unsigned qlo = (unsigned)__builtin_fmaf(w1[r],      QS, QB);
                const unsigned qhi = (unsigned)__builtin_fmaf(w1[r + 18], QS, QB);
                Wlq[pr * 9 + r][mcs] = (qlo & 0xffffu) | (qhi << 16);
            }
        }
        // ---- barrier A: LDS writes drained ----
        asm volatile("s_waitcnt lgkmcnt(0)" ::: "memory");
        __builtin_amdgcn_s_barrier();
        asm volatile("" ::: "memory");
        __builtin_amdgcn_sched_barrier(0);
        // ---- compute: 36 kp x (4 ds_read_b128 + 64 v_sad_u16) ----
        #pragma unroll 4
        for (int kp = 0; kp < KP; ++kp) {
            const uint4 pA = *(const uint4*)&Plq[kp][mh * 64 + tx * 8];
            const uint4 pB = *(const uint4*)&Plq[kp][mh * 64 + tx * 8 + 4];
            const uint4 wA = *(const uint4*)&Wlq[kp][fh * 64 + ty * 8];
            const uint4 wB = *(const uint4*)&Wlq[kp][fh * 64 + ty * 8 + 4];
            const unsigned pm[8] = {pA.x, pA.y, pA.z, pA.w,
                                    pB.x, pB.y, pB.z, pB.w};
            const unsigned wn[8] = {wA.x, wA.y, wA.z, wA.w,
                                    wB.x, wB.y, wB.z, wB.w};
            #pragma unroll
            for (int i = 0; i < 8; ++i)
                #pragma unroll
                for (int j = 0; j < 8; ++j)
                    acc[i][j] = sad16(pm[i], wn[j], acc[i][j]);
        }
        // ---- barrier B: reads consumed before next chunk's writes ----
        if (ch + 1 < nch) {
            asm volatile("" ::: "memory");
            __builtin_amdgcn_sched_barrier(0);
            __builtin_amdgcn_s_barrier();
            asm volatile("" ::: "memory");
        }
    }

    // ---- store: thread covers m = mt*128 + mh*64 + tx*8 .. +8 (8 | 784) ----
    const int mb = mt * TM + mh * 64 + tx * 8;
    const int bI = mb / L_;
    const int lb = mb - bI * L_;
    float* slab = direct ? dst : dst + (size_t)sp * SLAB;
    const float qs = (direct ? -1.0f : 1.0f) / QS;   // dequant + sign fold
    #pragma unroll
    for (int j = 0; j < 8; ++j) {
        const int f = fh * 64 + ty * 8 + j;
        float* o = &slab[(size_t)(bI * F_ + f) * L_ + lb];
        *(float4*)o       = make_float4(qs * (float)acc[0][j], qs * (float)acc[1][j],
                                        qs * (float)acc[2][j], qs * (float)acc[3][j]);
        *(float4*)(o + 4) = make_float4(qs * (float)acc[4][j], qs * (float)acc[5][j],
                                        qs * (float)acc[6][j], qs * (float)acc[7][j]);
    }
}

__global__ __launch_bounds__(256)
void adder2d_combine(const float* __restrict__ ws, float* __restrict__ out,
                     int nslab) {
    const int i = blockIdx.x * 256 + threadIdx.x;     // float4 index, SLAB/4 total
    float4 r = make_float4(0.0f, 0.0f, 0.0f, 0.0f);
    for (int s = 0; s < nslab; ++s) {
        const float4 p = ((const float4*)(ws + (size_t)s * SLAB))[i];
        r.x += p.x; r.y += p.y; r.z += p.z; r.w += p.w;
    }
    ((float4*)out)[i] = make_float4(-r.x, -r.y, -r.z, -r.w);
}

extern "C" void kernel_launch(void* const* d_in, const int* in_sizes, int n_in,
                              void* d_out, int out_size, void* d_ws, size_t ws_size,
                              hipStream_t stream) {
    const float* x = (const float*)d_in[0];   // [16,128,28,28]
    const float* W = (const float*)d_in[1];   // [128,128,3,3]
    float* out = (float*)d_out;               // [16,128,28,28]
    float* ws  = (float*)d_ws;

    if (ws_size >= (size_t)NSP * SLAB * sizeof(float)) {   // ~51.4 MB
        dim3 grid(NMT, 1, NSP);               // (98,1,8) = 784 4-wave blocks
        adder2d_main<<<grid, 256, 0, stream>>>(x, W, ws, NCH, 0);
        adder2d_combine<<<SLAB / 4 / 256, 256, 0, stream>>>(ws, out, NSP);
    } else {
        dim3 grid(NMT, 1, 1);                 // fallback: direct, full K
        adder2d_main<<<grid, 256, 0, stream>>>(x, W, out, C_ / BC, 1);
    }
}

// Round 19
// 120.398 us; speedup vs baseline: 2.0988x; 1.0015x over previous
//
#include <hip/hip_runtime.h>

// adder2d: out[b,f,l] = -sum_k |W[f,k] - P[b,k,l]|, P = 3x3/s1/p1 im2col of x.
// Round-19: r14's proven staging (shared, reg-prefetched, single-buffer LDS,
// two raw barriers/chunk) + r18's read-efficient 8m x 8f fragments, made
// compatible via k-split across wave-pairs: wave w = (f-half w&1, kp-half
// w>>1); waves 0/1 compute kp 0-8, waves 2/3 kp 9-17. Per thread per chunk:
// 9 kp x 4 ds_read_b128 / 576 v_sad_u16 (LDS stream 26.4 -> 17.6us at equal
// VALU). Epilogue: cross-wave k-reduction via LDS (4 passes x 4 uint4,
// staging buffer reused), waves 0/1 store. nsp=4 (combine traffic halved).

#define B_    16
#define C_    128
#define HH    28
#define WW    28
#define F_    128
#define L_    (HH * WW)          // 784
#define K_    (C_ * 9)           // 1152
#define M_    (B_ * L_)          // 12544 = 196 * 64 exactly
#define TM    64
#define BC    4                  // channels per chunk
#define KC    (BC * 9)           // 36 k per chunk
#define KP    (KC / 2)           // 18 packed pairs per chunk
#define NSP   4                  // K-split factor
#define NCH   ((C_ / BC) / NSP)  // 8 chunks per block
#define SLAB  (B_ * F_ * L_)     // 1,605,632 floats per partial slab
#define NMT   (M_ / TM)          // 196 m-tiles
#define QS    4096.0f            // u16 quantization scale (range +-8)
#define QB    32768.5f           // bias + 0.5 (round-half-up via cvt floor)

#define SMEMW (KP * TM + KP * F_)   // 3456 words: Plq | Wlq, reused as red

__device__ __forceinline__ unsigned sad16(unsigned a, unsigned b, unsigned c) {
    // D = |a.lo16 - b.lo16| + |a.hi16 - b.hi16| + c   (2 elems / inst)
    asm("v_sad_u16 %0, %1, %2, %0" : "+v"(c) : "v"(a), "v"(b));
    return c;
}

__global__ __launch_bounds__(256, 3)
void adder2d_main(const float* __restrict__ x, const float* __restrict__ Wg,
                  float* __restrict__ dst, int nch, int direct) {
    __shared__ __align__(16) unsigned smem[SMEMW];   // 13,824 B
    #define PLQ(kp, m) smem[(kp) * TM + (m)]
    #define WLQ(kp, f) smem[KP * TM + (kp) * F_ + (f)]

    const int t    = threadIdx.x;       // 0..255
    const int lane = t & 63;
    const int w    = t >> 6;            // wave 0..3
    const int tx   = lane & 7;          // m-group: 8 m each
    const int ty   = lane >> 3;         // f-group: 8 f each
    const int fh   = w & 1;             // wave's f-half (0/1)
    const int kh   = w >> 1;            // wave's kp-half (0/1)
    const int mt   = blockIdx.x, sp = blockIdx.z;
    const int c0   = sp * nch * BC;

    // ---- P identity: lane owns m = mt*64 + lane (same set in every wave) ----
    const int m  = mt * TM + lane;
    const int b  = m / L_;
    const int l  = m - b * L_;
    const int ho = l / WW, wo = l - ho * WW;
    int   toff[9];
    float sc[9];
    #pragma unroll
    for (int r = 0; r < 9; ++r) {
        const int dy = r / 3 - 1;
        const int dx = r - (r / 3) * 3 - 1;
        const bool ok = ((unsigned)(ho + dy) < (unsigned)HH) &&
                        ((unsigned)(wo + dx) < (unsigned)WW);
        toff[r] = ok ? (dy * WW + dx) : 0;   // safe addr; zeroed by sc
        sc[r]   = ok ? QS : 0.0f;            // masked -> quantize(0) = bias
    }
    const float* xb = x + (size_t)b * (C_ * L_) + l;

    // ---- staging roles (r14-proven, wave-uniform) ----
    // P: wave w stages pair cp = w>>1 (channels c8+cp, c8+cp+2),
    //    taps r in [r0, r0+5): waves 0/2 -> 0-4, waves 1/3 -> 5-8.
    const int cp = w >> 1;
    const int r0 = (w & 1) ? 5 : 0;
    // W: thread owns row fW = t>>1, pair-half pW = t&1 -> rows pW*9 + i.
    const int fW = t >> 1;
    const int pW = t & 1;
    const float* wbase = Wg + (size_t)fW * K_;

    unsigned acc[8][8];
    #pragma unroll
    for (int i = 0; i < 8; ++i)
        #pragma unroll
        for (int j = 0; j < 8; ++j) acc[i][j] = 0u;

    float ppre[10];     // P: 5 taps x 2 channels (5th unused for odd waves)
    float wpre[18];     // W: 9 taps x 2 channels

    auto loadP = [&](int c8) {
        const float* x1 = xb + (size_t)(c8 + cp) * L_;
        const float* x2 = x1 + 2 * L_;
        #pragma unroll
        for (int i = 0; i < 5; ++i) {
            const int r  = r0 + i;
            const int rr = (r > 8) ? 8 : r;      // clamp (dup load, not stored)
            ppre[i]     = x1[toff[rr]];
            ppre[5 + i] = x2[toff[rr]];
        }
    };
    auto loadW = [&](int c8) {
        const float* w1 = wbase + (size_t)(c8 + pW) * 9;
        #pragma unroll
        for (int i = 0; i < 9; ++i) {
            wpre[i]     = w1[i];
            wpre[9 + i] = w1[18 + i];
        }
    };

    loadP(c0);
    loadW(c0);

    #pragma unroll 1
    for (int ch = 0; ch < nch; ++ch) {
        // ---- write staged regs -> LDS (quantize + pack inline) ----
        #pragma unroll
        for (int i = 0; i < 5; ++i) {
            const int r = r0 + i;
            if (r <= 8) {
                const unsigned qlo = (unsigned)__builtin_fmaf(ppre[i],     sc[r], QB);
                const unsigned qhi = (unsigned)__builtin_fmaf(ppre[5 + i], sc[r], QB);
                PLQ(cp * 9 + r, lane) = (qlo & 0xffffu) | (qhi << 16);
            }
        }
        #pragma unroll
        for (int i = 0; i < 9; ++i) {
            const unsigned qlo = (unsigned)__builtin_fmaf(wpre[i],     QS, QB);
            const unsigned qhi = (unsigned)__builtin_fmaf(wpre[9 + i], QS, QB);
            WLQ(pW * 9 + i, fW) = (qlo & 0xffffu) | (qhi << 16);
        }
        // ---- prefetch next chunk (stays in flight across the barrier) ----
        if (ch + 1 < nch) {
            loadP(c0 + (ch + 1) * BC);
            loadW(c0 + (ch + 1) * BC);
        }
        // ---- barrier A: LDS writes drained, vmcnt NOT drained ----
        asm volatile("s_waitcnt lgkmcnt(0)" ::: "memory");
        __builtin_amdgcn_s_barrier();
        asm volatile("" ::: "memory");
        __builtin_amdgcn_sched_barrier(0);
        // ---- compute: 9 kp (this wave's half) x (4 ds_read_b128 + 64 sads)
        #pragma unroll
        for (int kk = 0; kk < 9; ++kk) {
            const int kp = kh * 9 + kk;
            const uint4 pA = *(const uint4*)&PLQ(kp, tx * 8);
            const uint4 pB = *(const uint4*)&PLQ(kp, tx * 8 + 4);
            const uint4 wA = *(const uint4*)&WLQ(kp, fh * 64 + ty * 8);
            const uint4 wB = *(const uint4*)&WLQ(kp, fh * 64 + ty * 8 + 4);
            const unsigned pm[8] = {pA.x, pA.y, pA.z, pA.w,
                                    pB.x, pB.y, pB.z, pB.w};
            const unsigned wn[8] = {wA.x, wA.y, wA.z, wA.w,
                                    wB.x, wB.y, wB.z, wB.w};
            #pragma unroll
            for (int i = 0; i < 8; ++i)
                #pragma unroll
                for (int j = 0; j < 8; ++j)
                    acc[i][j] = sad16(pm[i], wn[j], acc[i][j]);
        }
        // ---- barrier B: reads consumed before next chunk's writes ----
        if (ch + 1 < nch) {
            asm volatile("" ::: "memory");
            __builtin_amdgcn_sched_barrier(0);
            __builtin_amdgcn_s_barrier();
            asm volatile("" ::: "memory");
        }
    }

    // ---- epilogue: cross-wave k-reduction (pairs (0,2),(1,3) share fh) ----
    // waves kh=1 write acc into smem (reused); waves kh=0 read+add.
    asm volatile("" ::: "memory");
    __builtin_amdgcn_sched_barrier(0);
    __builtin_amdgcn_s_barrier();          // all compute reads of smem done
    asm volatile("" ::: "memory");
    unsigned* red = smem;                  // slot = fh*64+lane, 16 words each
    const int slot = (fh * 64 + lane) * 16;
    #pragma unroll
    for (int p = 0; p < 4; ++p) {
        if (kh == 1) {
            #pragma unroll
            for (int q = 0; q < 4; ++q) {
                const int v = p * 16 + q * 4;
                uint4 val;
                val.x = acc[(v + 0) >> 3][(v + 0) & 7];
                val.y = acc[(v + 1) >> 3][(v + 1) & 7];
                val.z = acc[(v + 2) >> 3][(v + 2) & 7];
                val.w = acc[(v + 3) >> 3][(v + 3) & 7];
                *(uint4*)&red[slot + q * 4] = val;
            }
        }
        asm volatile("s_waitcnt lgkmcnt(0)" ::: "memory");
        __builtin_amdgcn_s_barrier();
        asm volatile("" ::: "memory");
        if (kh == 0) {
            #pragma unroll
            for (int q = 0; q < 4; ++q) {
                const int v = p * 16 + q * 4;
                const uint4 r2 = *(const uint4*)&red[slot + q * 4];
                acc[(v + 0) >> 3][(v + 0) & 7] += r2.x;
                acc[(v + 1) >> 3][(v + 1) & 7] += r2.y;
                acc[(v + 2) >> 3][(v + 2) & 7] += r2.z;
                acc[(v + 3) >> 3][(v + 3) & 7] += r2.w;
            }
        }
        if (p < 3) {
            asm volatile("" ::: "memory");
            __builtin_amdgcn_sched_barrier(0);
            __builtin_amdgcn_s_barrier();
            asm volatile("" ::: "memory");
        }
    }

    // ---- store (waves kh=0 only): m = mt*64 + tx*8 .. +8 (8 | 784) ----
    if (kh == 0) {
        const int mb = mt * TM + tx * 8;
        const int bI = mb / L_;
        const int lb = mb - bI * L_;
        float* slab = direct ? dst : dst + (size_t)sp * SLAB;
        const float qs = (direct ? -1.0f : 1.0f) / QS;   // dequant + sign fold
        #pragma unroll
        for (int j = 0; j < 8; ++j) {
            const int f = fh * 64 + ty * 8 + j;
            float* o = &slab[(size_t)(bI * F_ + f) * L_ + lb];
            *(float4*)o       = make_float4(qs * (float)acc[0][j],
                                            qs * (float)acc[1][j],
                                            qs * (float)acc[2][j],
                                            qs * (float)acc[3][j]);
            *(float4*)(o + 4) = make_float4(qs * (float)acc[4][j],
                                            qs * (float)acc[5][j],
                                            qs * (float)acc[6][j],
                                            qs * (float)acc[7][j]);
        }
    }
    #undef PLQ
    #undef WLQ
}

__global__ __launch_bounds__(256)
void adder2d_combine(const float* __restrict__ ws, float* __restrict__ out,
                     int nslab) {
    const int i = blockIdx.x * 256 + threadIdx.x;     // float4 index, SLAB/4 total
    float4 r = make_float4(0.0f, 0.0f, 0.0f, 0.0f);
    for (int s = 0; s < nslab; ++s) {
        const float4 p = ((const float4*)(ws + (size_t)s * SLAB))[i];
        r.x += p.x; r.y += p.y; r.z += p.z; r.w += p.w;
    }
    ((float4*)out)[i] = make_float4(-r.x, -r.y, -r.z, -r.w);
}

extern "C" void kernel_launch(void* const* d_in, const int* in_sizes, int n_in,
                              void* d_out, int out_size, void* d_ws, size_t ws_size,
                              hipStream_t stream) {
    const float* x = (const float*)d_in[0];   // [16,128,28,28]
    const float* W = (const float*)d_in[1];   // [128,128,3,3]
    float* out = (float*)d_out;               // [16,128,28,28]
    float* ws  = (float*)d_ws;

    if (ws_size >= (size_t)NSP * SLAB * sizeof(float)) {   // ~25.7 MB
        dim3 grid(NMT, 1, NSP);               // (196,1,4) = 784 4-wave blocks
        adder2d_main<<<grid, 256, 0, stream>>>(x, W, ws, NCH, 0);
        adder2d_combine<<<SLAB / 4 / 256, 256, 0, stream>>>(ws, out, NSP);
    } else {
        dim3 grid(NMT, 1, 1);                 // fallback: direct, full K
        adder2d_main<<<grid, 256, 0, stream>>>(x, W, out, C_ / BC, 1);
    }
}

// Round 20
// 113.426 us; speedup vs baseline: 2.2278x; 1.0615x over previous
//
#include <hip/hip_runtime.h>

// adder2d: out[b,f,l] = -sum_k |W[f,k] - P[b,k,l]|, P = 3x3/s1/p1 im2col of x.
// FINAL (r20) = r14, the session-best measured config (112.8us total):
// 4-wave blocks, 64m x 128f tile, per-thread 8m x 4f, v_sad_u16 on u16
// k-pair-packed operands (scale 4096, bias 32768; worst-case output error
// 0.28 << 4.0 tolerance), shared cross-wave staging with register prefetch,
// SINGLE-buffer LDS 13.8KB, two raw s_barriers per chunk (lgkmcnt-only
// drain; prefetch vmcnt stays in flight), K-split x8 slabs + combine with
// the slab loop unrolled at compile time. launch_bounds(256,4): VGPR cap
// 128 covers the live set -> no spill (r13's (256,6) spilled; r8/r13/r17
// all showed spill/atomic/fence variants regress).
//
// Session floor analysis: main = 55us ~= 26.5us LDS-pipe + 23.4us VALU
// (serialized; overlap attempts r12/r18/r19 all regressed); total - kernels
// ~= 45us harness-fixed launch/graph overhead (r17: 1 launch, same gap).

#define B_    16
#define C_    128
#define HH    28
#define WW    28
#define F_    128
#define L_    (HH * WW)          // 784
#define K_    (C_ * 9)           // 1152
#define M_    (B_ * L_)          // 12544 = 196 * 64 exactly
#define TM    64
#define BC    4                  // channels per chunk
#define KC    (BC * 9)           // 36 k per chunk
#define KP    (KC / 2)           // 18 packed pairs per chunk
#define NSP   8                  // K-split factor
#define NCH   ((C_ / BC) / NSP)  // 4 chunks per block
#define SLAB  (B_ * F_ * L_)     // 1,605,632 floats per partial slab
#define NMT   (M_ / TM)          // 196 m-tiles
#define QS    4096.0f            // u16 quantization scale (range +-8)
#define QB    32768.5f           // bias + 0.5 (round-half-up via cvt floor)

__device__ __forceinline__ unsigned sad16(unsigned a, unsigned b, unsigned c) {
    // D = |a.lo16 - b.lo16| + |a.hi16 - b.hi16| + c   (2 elems / inst)
    asm("v_sad_u16 %0, %1, %2, %0" : "+v"(c) : "v"(a), "v"(b));
    return c;
}

__global__ __launch_bounds__(256, 4)
void adder2d_main(const float* __restrict__ x, const float* __restrict__ Wg,
                  float* __restrict__ dst, int nch, int direct) {
    __shared__ __align__(16) unsigned Plq[KP][TM];   //  4,608 B
    __shared__ __align__(16) unsigned Wlq[KP][F_];   //  9,216 B

    const int t    = threadIdx.x;       // 0..255
    const int lane = t & 63;
    const int w    = t >> 6;            // wave 0..3
    const int tx   = lane & 7;          // m-group: 8 m each
    const int ty   = lane >> 3;         // f-group: 4 f each
    const int fw   = 32 * w;            // wave's f slice base
    const int mt   = blockIdx.x, sp = blockIdx.z;
    const int c0   = sp * nch * BC;

    // ---- P identity: lane owns m = mt*64 + lane (same set in every wave) ----
    const int m  = mt * TM + lane;
    const int b  = m / L_;
    const int l  = m - b * L_;
    const int ho = l / WW, wo = l - ho * WW;
    int   toff[9];
    float sc[9];
    #pragma unroll
    for (int r = 0; r < 9; ++r) {
        const int dy = r / 3 - 1;
        const int dx = r - (r / 3) * 3 - 1;
        const bool ok = ((unsigned)(ho + dy) < (unsigned)HH) &&
                        ((unsigned)(wo + dx) < (unsigned)WW);
        toff[r] = ok ? (dy * WW + dx) : 0;   // safe addr; zeroed by sc
        sc[r]   = ok ? QS : 0.0f;            // masked -> quantize(0) = bias
    }
    const float* xb = x + (size_t)b * (C_ * L_) + l;

    // ---- staging roles (wave-uniform) ----
    // P: wave w stages channel-pair cp = w>>1 (channels c8+cp, c8+cp+2),
    //    taps r in [r0, r0+5): waves 0/2 -> taps 0-4, waves 1/3 -> 5-8.
    const int cp = w >> 1;
    const int r0 = (w & 1) ? 5 : 0;
    // W: thread owns row fW = t>>1, pair-half pW = t&1 -> words kp = pW*9 + i.
    const int fW = t >> 1;
    const int pW = t & 1;
    const float* wbase = Wg + (size_t)fW * K_;

    unsigned acc[8][4];
    #pragma unroll
    for (int i = 0; i < 8; ++i)
        #pragma unroll
        for (int j = 0; j < 4; ++j) acc[i][j] = 0u;

    // ---- prefetch registers ----
    float ppre[10];     // P: 5 taps x 2 channels (5th unused for odd waves)
    float wpre[18];     // W: 9 taps x 2 channels

    auto loadP = [&](int c8) {
        const float* x1 = xb + (size_t)(c8 + cp) * L_;
        const float* x2 = x1 + 2 * L_;
        #pragma unroll
        for (int i = 0; i < 5; ++i) {
            const int r  = r0 + i;
            const int rr = (r > 8) ? 8 : r;      // clamp (dup load, not stored)
            ppre[i]     = x1[toff[rr]];
            ppre[5 + i] = x2[toff[rr]];
        }
    };
    auto loadW = [&](int c8) {
        const float* w1 = wbase + (size_t)(c8 + pW) * 9;
        #pragma unroll
        for (int i = 0; i < 9; ++i) {            // consecutive -> merged loads
            wpre[i]     = w1[i];
            wpre[9 + i] = w1[18 + i];            // channel c8+pW+2
        }
    };

    loadP(c0);
    loadW(c0);

    #pragma unroll 1
    for (int ch = 0; ch < nch; ++ch) {
        // ---- write staged regs -> LDS (quantize + pack inline) ----
        #pragma unroll
        for (int i = 0; i < 5; ++i) {
            const int r = r0 + i;
            if (r <= 8) {
                const unsigned qlo = (unsigned)__builtin_fmaf(ppre[i],     sc[r], QB);
                const unsigned qhi = (unsigned)__builtin_fmaf(ppre[5 + i], sc[r], QB);
                Plq[cp * 9 + r][lane] = (qlo & 0xffffu) | (qhi << 16);
            }
        }
        #pragma unroll
        for (int i = 0; i < 9; ++i) {
            const unsigned qlo = (unsigned)__builtin_fmaf(wpre[i],     QS, QB);
            const unsigned qhi = (unsigned)__builtin_fmaf(wpre[9 + i], QS, QB);
            Wlq[pW * 9 + i][fW] = (qlo & 0xffffu) | (qhi << 16);
        }
        // ---- prefetch next chunk (stays in flight across the barrier) ----
        if (ch + 1 < nch) {
            loadP(c0 + (ch + 1) * BC);
            loadW(c0 + (ch + 1) * BC);
        }
        // ---- barrier A: LDS writes drained, vmcnt NOT drained ----
        asm volatile("s_waitcnt lgkmcnt(0)" ::: "memory");
        __builtin_amdgcn_s_barrier();
        asm volatile("" ::: "memory");
        __builtin_amdgcn_sched_barrier(0);
        // ---- compute: 18 kp x (3 ds_read_b128 + 32 v_sad_u16) ----
        #pragma unroll 6
        for (int kp = 0; kp < KP; ++kp) {
            const uint4 pA = *(const uint4*)&Plq[kp][tx * 8];
            const uint4 pB = *(const uint4*)&Plq[kp][tx * 8 + 4];
            const uint4 wA = *(const uint4*)&Wlq[kp][fw + ty * 4];
            const unsigned pm[8] = {pA.x, pA.y, pA.z, pA.w,
                                    pB.x, pB.y, pB.z, pB.w};
            const unsigned wn[4] = {wA.x, wA.y, wA.z, wA.w};
            #pragma unroll
            for (int i = 0; i < 8; ++i)
                #pragma unroll
                for (int j = 0; j < 4; ++j)
                    acc[i][j] = sad16(pm[i], wn[j], acc[i][j]);
        }
        // ---- barrier B: every wave's reads of this buffer are consumed
        // (data deps drained lgkmcnt) before anyone's next-chunk writes ----
        if (ch + 1 < nch) {
            asm volatile("" ::: "memory");
            __builtin_amdgcn_sched_barrier(0);
            __builtin_amdgcn_s_barrier();
            asm volatile("" ::: "memory");
        }
    }

    // ---- store: thread covers m = mt*64 + tx*8 .. +8 (8 | 784: no straddle)
    const int mb = mt * TM + tx * 8;
    const int bI = mb / L_;
    const int lb = mb - bI * L_;
    float* slab = direct ? dst : dst + (size_t)sp * SLAB;
    const float qs = (direct ? -1.0f : 1.0f) / QS;   // dequant + sign fold
    #pragma unroll
    for (int j = 0; j < 4; ++j) {
        const int f = fw + ty * 4 + j;
        float* o = &slab[(size_t)(bI * F_ + f) * L_ + lb];
        *(float4*)o       = make_float4(qs * (float)acc[0][j], qs * (float)acc[1][j],
                                        qs * (float)acc[2][j], qs * (float)acc[3][j]);
        *(float4*)(o + 4) = make_float4(qs * (float)acc[4][j], qs * (float)acc[5][j],
                                        qs * (float)acc[6][j], qs * (float)acc[7][j]);
    }
}

__global__ __launch_bounds__(256)
void adder2d_combine(const float* __restrict__ ws, float* __restrict__ out) {
    const int i = blockIdx.x * 256 + threadIdx.x;     // float4 index, SLAB/4 total
    float4 r = make_float4(0.0f, 0.0f, 0.0f, 0.0f);
    #pragma unroll
    for (int s = 0; s < NSP; ++s) {                   // compile-time unrolled:
        const float4 p = ((const float4*)(ws + (size_t)s * SLAB))[i];
        r.x += p.x; r.y += p.y; r.z += p.z; r.w += p.w;
    }
    ((float4*)out)[i] = make_float4(-r.x, -r.y, -r.z, -r.w);
}

__global__ __launch_bounds__(256)
void adder2d_combine4(const float* __restrict__ ws, float* __restrict__ out) {
    const int i = blockIdx.x * 256 + threadIdx.x;
    float4 r = make_float4(0.0f, 0.0f, 0.0f, 0.0f);
    #pragma unroll
    for (int s = 0; s < 4; ++s) {
        const float4 p = ((const float4*)(ws + (size_t)s * SLAB))[i];
        r.x += p.x; r.y += p.y; r.z += p.z; r.w += p.w;
    }
    ((float4*)out)[i] = make_float4(-r.x, -r.y, -r.z, -r.w);
}

extern "C" void kernel_launch(void* const* d_in, const int* in_sizes, int n_in,
                              void* d_out, int out_size, void* d_ws, size_t ws_size,
                              hipStream_t stream) {
    const float* x = (const float*)d_in[0];   // [16,128,28,28]
    const float* W = (const float*)d_in[1];   // [128,128,3,3]
    float* out = (float*)d_out;               // [16,128,28,28]
    float* ws  = (float*)d_ws;

    if (ws_size >= (size_t)NSP * SLAB * sizeof(float)) {       // ~51.4 MB
        dim3 grid(NMT, 1, NSP);               // (196,1,8) = 1568 4-wave blocks
        adder2d_main<<<grid, 256, 0, stream>>>(x, W, ws, NCH, 0);
        adder2d_combine<<<SLAB / 4 / 256, 256, 0, stream>>>(ws, out);
    } else if (ws_size >= (size_t)4 * SLAB * sizeof(float)) {  // ~25.7 MB
        dim3 grid(NMT, 1, 4);
        adder2d_main<<<grid, 256, 0, stream>>>(x, W, ws, (C_ / BC) / 4, 0);
        adder2d_combine4<<<SLAB / 4 / 256, 256, 0, stream>>>(ws, out);
    } else {
        dim3 grid(NMT, 1, 1);                 // fallback: direct, full K
        adder2d_main<<<grid, 256, 0, stream>>>(x, W, out, C_ / BC, 1);
    }
}